// Round 1
// baseline (3885.514 us; speedup 1.0000x reference)
//
#include <hip/hip_runtime.h>

#define NS 8192
#define TT 128
#define DD 64
#define HH 512
#define BM 16
#define NSTEP 127

__global__ __launch_bounds__(256) void ode_ab4_kernel(
    const float* __restrict__ ts, const float* __restrict__ hxs,
    const float* __restrict__ masks, const float* __restrict__ W1,
    const float* __restrict__ b1, const float* __restrict__ W2,
    const float* __restrict__ b2, float* __restrict__ out)
{
  __shared__ float Ys[BM][DD];   // current state tile
  __shared__ float Zs[BM][HH];   // hidden activations
  __shared__ float DTs[BM][TT];  // per-sample dt table

  const int t = threadIdx.x;
  const int w = t >> 6, l = t & 63;
  const int m0 = blockIdx.x * BM;
  const int jb = (w << 7) + (l << 1); // layer-1 cols: 128*w + 2*l

  // Per-thread owned samples: m_local = 4*w + i, dim d = l.
  float y[4], f1[4], f2[4], f3[4];
  #pragma unroll
  for (int i = 0; i < 4; ++i) {
    int m = (w << 2) + i;
    float mk = masks[m0 + m];
    float v = hxs[(m0 + m) * DD + l] * mk;
    y[i] = v; f1[i] = 0.f; f2[i] = 0.f; f3[i] = 0.f;
    Ys[m][l] = v;
  }
  // dt table (history-init zeros are provably never used by the AB startup)
  for (int idx = t; idx < BM * TT; idx += 256) {
    int m = idx >> 7, s = idx & (TT - 1);
    float v = 0.f;
    if (s < TT - 1)
      v = ts[(m0 + m) * TT + s + 1] - ts[(m0 + m) * TT + s];
    DTs[m][s] = v;
  }
  const float b1a = b1[jb], b1b = b1[jb + 1];
  const float b2l = b2[l];
  __syncthreads();

  for (int s = 0; s < NSTEP; ++s) {
    // ---------- layer 1: z[m][jb..jb+1] = tanh(y @ W1 + b1), all 16 m ----------
    float a0[BM], a1[BM];
    #pragma unroll
    for (int m = 0; m < BM; ++m) { a0[m] = b1a; a1[m] = b1b; }
    for (int d = 0; d < DD; d += 4) {
      float2 wv[4];
      #pragma unroll
      for (int dd = 0; dd < 4; ++dd)
        wv[dd] = *(const float2*)&W1[(d + dd) * HH + jb]; // coalesced 8B/lane
      #pragma unroll
      for (int m = 0; m < BM; ++m) {
        float4 ym = *(const float4*)&Ys[m][d];            // LDS broadcast
        a0[m] += ym.x * wv[0].x + ym.y * wv[1].x + ym.z * wv[2].x + ym.w * wv[3].x;
        a1[m] += ym.x * wv[0].y + ym.y * wv[1].y + ym.z * wv[2].y + ym.w * wv[3].y;
      }
    }
    #pragma unroll
    for (int m = 0; m < BM; ++m) {
      float2 z; z.x = tanhf(a0[m]); z.y = tanhf(a1[m]);
      *(float2*)&Zs[m][jb] = z;
    }
    __syncthreads();

    // ---------- layer 2: fn[m][l] = Z[m] @ W2[:,l] + b2[l], m = 4w+i ----------
    float acc[4] = {0.f, 0.f, 0.f, 0.f};
    for (int j = 0; j < HH; j += 4) {
      const float* w2p = &W2[j * DD + l];                 // coalesced b32 x4
      float w0 = w2p[0], w1_ = w2p[DD], w2_ = w2p[2 * DD], w3_ = w2p[3 * DD];
      #pragma unroll
      for (int i = 0; i < 4; ++i) {
        float4 zv = *(const float4*)&Zs[(w << 2) + i][j]; // LDS broadcast
        acc[i] += zv.x * w0 + zv.y * w1_ + zv.z * w2_ + zv.w * w3_;
      }
    }
    #pragma unroll
    for (int i = 0; i < 4; ++i) {
      int m = (w << 2) + i;
      float fn = acc[i] + b2l;
      float dtv = DTs[m][s];
      float inc;
      if (s == 0)      inc = fn;                                            // AB1
      else if (s == 1) inc = (3.f * fn - f1[i]) * 0.5f;                     // AB2
      else if (s == 2) inc = (23.f * fn - 16.f * f1[i] + 5.f * f2[i]) * (1.f / 12.f);   // AB3
      else             inc = (55.f * fn - 59.f * f1[i] + 37.f * f2[i] - 9.f * f3[i]) * (1.f / 24.f); // AB4
      y[i] += dtv * inc;
      f3[i] = f2[i]; f2[i] = f1[i]; f1[i] = fn;
      Ys[m][l] = y[i];
    }
    __syncthreads();
  }

  // pred = where(ts[:,0]==0, first_point, y_final)
  #pragma unroll
  for (int i = 0; i < 4; ++i) {
    int m = m0 + (w << 2) + i;
    float fp = hxs[m * DD + l] * masks[m];
    float ts0 = ts[m * TT];
    out[m * DD + l] = (ts0 == 0.f) ? fp : y[i];
  }
}

extern "C" void kernel_launch(void* const* d_in, const int* in_sizes, int n_in,
                              void* d_out, int out_size, void* d_ws, size_t ws_size,
                              hipStream_t stream) {
  const float* ts    = (const float*)d_in[0];
  const float* hxs   = (const float*)d_in[1];
  const float* masks = (const float*)d_in[2];
  const float* W1    = (const float*)d_in[3];
  const float* b1    = (const float*)d_in[4];
  const float* W2    = (const float*)d_in[5];
  const float* b2    = (const float*)d_in[6];
  float* out = (float*)d_out;
  (void)in_sizes; (void)n_in; (void)out_size; (void)d_ws; (void)ws_size;

  dim3 grid(NS / BM), block(256);
  ode_ab4_kernel<<<grid, block, 0, stream>>>(ts, hxs, masks, W1, b1, W2, b2, out);
}

// Round 2
// 1947.497 us; speedup vs baseline: 1.9951x; 1.9951x over previous
//
#include <hip/hip_runtime.h>

#define NS 8192
#define TT 128
#define DD 64
#define HH 512
#define BM 32
#define NSTEP (TT - 1)
#define LO_SCALE 2048.0f
#define LO_INV (1.0f / 2048.0f)

typedef _Float16 half8 __attribute__((ext_vector_type(8)));
typedef float f32x4 __attribute__((ext_vector_type(4)));

// ws layout (_Float16 elements):
//   W1Th [HH][DD] @ 0        (hi of W1^T)
//   W1Tl [HH][DD] @ 32768    (lo*2048 of W1^T)
//   W2Th [DD][HH] @ 65536    (hi of W2^T)
//   W2Tl [DD][HH] @ 98304    (lo*2048 of W2^T)

__global__ __launch_bounds__(256) void prep_weights(
    const float* __restrict__ W1, const float* __restrict__ W2,
    _Float16* __restrict__ wsp) {
  int idx = blockIdx.x * 256 + threadIdx.x;  // 0..65535
  if (idx < HH * DD) {                       // W1[d][j], d=idx/HH, j=idx%HH
    int d = idx / HH, j = idx % HH;
    float w0 = W1[idx];
    _Float16 h = (_Float16)w0;
    float r = (w0 - (float)h) * LO_SCALE;
    wsp[j * DD + d] = h;
    wsp[HH * DD + j * DD + d] = (_Float16)r;
  } else {                                   // W2[j][d]
    int k = idx - HH * DD;
    int j = k / DD, d = k % DD;
    float w0 = W2[k];
    _Float16 h = (_Float16)w0;
    float r = (w0 - (float)h) * LO_SCALE;
    wsp[2 * HH * DD + d * HH + j] = h;
    wsp[3 * HH * DD + d * HH + j] = (_Float16)r;
  }
}

__device__ __forceinline__ float fast_tanh(float x) {
  float ax = fabsf(x);
  float e = __expf(-2.0f * ax);              // e^{-2|x|}
  float r = (1.0f - e) / (1.0f + e);         // tanh(|x|)
  return (x < 0.0f) ? -r : r;
}

__global__ __launch_bounds__(512) void ode_mfma_kernel(
    const float* __restrict__ ts, const float* __restrict__ hxs,
    const float* __restrict__ masks, const float* __restrict__ b1,
    const float* __restrict__ b2, const _Float16* __restrict__ wsp,
    float* __restrict__ out) {
  __shared__ _Float16 Yh[BM][72], Yl[BM][72];    // state, fp16 split (72: 2-way-free)
  __shared__ _Float16 Zh[BM][520], Zl[BM][520];  // hidden, fp16 split (520: 2-way-free)
  __shared__ float DTs[BM][129];                 // dt table (129: conflict-free)

  const int t = threadIdx.x;
  const int w = t >> 6;            // wave 0..7
  const int l = t & 63;
  const int c = l & 15;            // fragment col/row index
  const int q = l >> 4;            // k-group / row-group
  const int m0 = blockIdx.x * BM;
  const int db = w >> 1;           // phase-B d-tile (0..3)
  const int mb = w & 1;            // phase-B m-tile (0..1)
  const int m = mb * 16 + c;       // sample owned in phase B
  const int d0 = db * 16 + 4 * q;  // first of 4 owned dims

  const _Float16* W1Th = wsp;
  const _Float16* W1Tl = wsp + HH * DD;
  const _Float16* W2Th = wsp + 2 * HH * DD;
  const _Float16* W2Tl = wsp + 3 * HH * DD;

  // dt table
  for (int idx = t; idx < BM * TT; idx += 512) {
    int mm = idx >> 7, s = idx & (TT - 1);
    float v = 0.0f;
    if (s < NSTEP) v = ts[(m0 + mm) * TT + s + 1] - ts[(m0 + mm) * TT + s];
    DTs[mm][s] = v;
  }

  // init state: y = hxs * mask (each lane owns (m, d0..d0+3))
  const float mk = masks[m0 + m];
  f32x4 y0 = *(const f32x4*)&hxs[(m0 + m) * DD + d0];
  float y[4], f1[4], f2[4], f3[4];
#pragma unroll
  for (int r = 0; r < 4; ++r) {
    y[r] = y0[r] * mk;
    f1[r] = f2[r] = f3[r] = 0.0f;  // never consumed before being overwritten
    _Float16 h = (_Float16)y[r];
    Yh[m][d0 + r] = h;
    Yl[m][d0 + r] = (_Float16)((y[r] - (float)h) * LO_SCALE);
  }

  // biases (b1 cols fixed per wave; b2 dims fixed per lane)
  float b1v[4], b2v[4];
#pragma unroll
  for (int i = 0; i < 4; ++i) b1v[i] = b1[(4 * w + i) * 16 + c];
#pragma unroll
  for (int r = 0; r < 4; ++r) b2v[r] = b2[d0 + r];

  __syncthreads();

  for (int s = 0; s < NSTEP; ++s) {
    // ---- phase A: Z = tanh(Y @ W1 + b1); M=32 samples, N=512 hidden, K=64 ----
    // tiles: (mbt in 0..1) x (jb in 0..31); wave w owns jb in {4w..4w+3}
    for (int tt = 0; tt < 8; ++tt) {
      const int jb = 4 * w + (tt & 3);
      const int mbt = tt >> 2;
      const float bb = b1v[tt & 3];
      f32x4 acc1 = {bb, bb, bb, bb};
      f32x4 acc2 = {0.0f, 0.0f, 0.0f, 0.0f};
#pragma unroll
      for (int kk = 0; kk < 2; ++kk) {
        half8 ah = *(const half8*)&Yh[mbt * 16 + c][kk * 32 + 8 * q];
        half8 al = *(const half8*)&Yl[mbt * 16 + c][kk * 32 + 8 * q];
        half8 bh = *(const half8*)&W1Th[(jb * 16 + c) * DD + kk * 32 + 8 * q];
        half8 bl = *(const half8*)&W1Tl[(jb * 16 + c) * DD + kk * 32 + 8 * q];
        acc1 = __builtin_amdgcn_mfma_f32_16x16x32_f16(ah, bh, acc1, 0, 0, 0);
        acc2 = __builtin_amdgcn_mfma_f32_16x16x32_f16(ah, bl, acc2, 0, 0, 0);
        acc2 = __builtin_amdgcn_mfma_f32_16x16x32_f16(al, bh, acc2, 0, 0, 0);
      }
#pragma unroll
      for (int r = 0; r < 4; ++r) {
        float zf = fast_tanh(acc1[r] + acc2[r] * LO_INV);
        _Float16 h = (_Float16)zf;
        int zr = mbt * 16 + 4 * q + r, zc = jb * 16 + c;
        Zh[zr][zc] = h;
        Zl[zr][zc] = (_Float16)((zf - (float)h) * LO_SCALE);
      }
    }
    __syncthreads();

    // ---- phase B (swapped): F^T = W2^T @ Z^T; M=64 dims, N=32 samples, K=512 ----
    // one 16x16 tile per wave: rows d0.., cols m
    {
      f32x4 acc1 = {b2v[0], b2v[1], b2v[2], b2v[3]};
      f32x4 acc2 = {0.0f, 0.0f, 0.0f, 0.0f};
#pragma unroll 4
      for (int kk = 0; kk < 16; ++kk) {
        half8 ah = *(const half8*)&W2Th[(db * 16 + c) * HH + kk * 32 + 8 * q];
        half8 al = *(const half8*)&W2Tl[(db * 16 + c) * HH + kk * 32 + 8 * q];
        half8 bh = *(const half8*)&Zh[mb * 16 + c][kk * 32 + 8 * q];
        half8 bl = *(const half8*)&Zl[mb * 16 + c][kk * 32 + 8 * q];
        acc1 = __builtin_amdgcn_mfma_f32_16x16x32_f16(ah, bh, acc1, 0, 0, 0);
        acc2 = __builtin_amdgcn_mfma_f32_16x16x32_f16(ah, bl, acc2, 0, 0, 0);
        acc2 = __builtin_amdgcn_mfma_f32_16x16x32_f16(al, bh, acc2, 0, 0, 0);
      }
      const float dtv = DTs[m][s];
#pragma unroll
      for (int r = 0; r < 4; ++r) {
        float fn = acc1[r] + acc2[r] * LO_INV;
        float inc;
        if (s == 0)      inc = fn;
        else if (s == 1) inc = (3.0f * fn - f1[r]) * 0.5f;
        else if (s == 2) inc = (23.0f * fn - 16.0f * f1[r] + 5.0f * f2[r]) * (1.0f / 12.0f);
        else             inc = (55.0f * fn - 59.0f * f1[r] + 37.0f * f2[r] - 9.0f * f3[r]) * (1.0f / 24.0f);
        y[r] += dtv * inc;
        f3[r] = f2[r]; f2[r] = f1[r]; f1[r] = fn;
        _Float16 h = (_Float16)y[r];
        Yh[m][d0 + r] = h;
        Yl[m][d0 + r] = (_Float16)((y[r] - (float)h) * LO_SCALE);
      }
    }
    __syncthreads();
  }

  // pred = where(ts[:,0]==0, first_point, y_final)
  float ts0 = ts[(m0 + m) * TT];
  f32x4 o;
  if (ts0 == 0.0f) {
    f32x4 h4 = *(const f32x4*)&hxs[(m0 + m) * DD + d0];
#pragma unroll
    for (int r = 0; r < 4; ++r) o[r] = h4[r] * mk;
  } else {
#pragma unroll
    for (int r = 0; r < 4; ++r) o[r] = y[r];
  }
  *(f32x4*)&out[(m0 + m) * DD + d0] = o;
}

extern "C" void kernel_launch(void* const* d_in, const int* in_sizes, int n_in,
                              void* d_out, int out_size, void* d_ws, size_t ws_size,
                              hipStream_t stream) {
  const float* ts    = (const float*)d_in[0];
  const float* hxs   = (const float*)d_in[1];
  const float* masks = (const float*)d_in[2];
  const float* W1    = (const float*)d_in[3];
  const float* b1    = (const float*)d_in[4];
  const float* W2    = (const float*)d_in[5];
  const float* b2    = (const float*)d_in[6];
  float* out = (float*)d_out;
  _Float16* wsp = (_Float16*)d_ws;
  (void)in_sizes; (void)n_in; (void)out_size; (void)ws_size;

  prep_weights<<<dim3((2 * HH * DD) / 256), dim3(256), 0, stream>>>(W1, W2, wsp);
  ode_mfma_kernel<<<dim3(NS / BM), dim3(512), 0, stream>>>(ts, hxs, masks, b1, b2, wsp, out);
}

// Round 4
// 502.518 us; speedup vs baseline: 7.7321x; 3.8755x over previous
//
#include <hip/hip_runtime.h>

// Resubmission: round-3 bench died with an infra error (UnresponsiveContainer)
// before measuring this kernel. Source identical to round-3 submission.

#define NS 8192
#define TT 128
#define DD 64
#define HH 512
#define BM 32
#define NSTEP (TT - 1)
#define LO_SCALE 2048.0f
#define LO_INV (1.0f / 2048.0f)

typedef _Float16 half8 __attribute__((ext_vector_type(8)));
typedef _Float16 half4 __attribute__((ext_vector_type(4)));
typedef float f32x4 __attribute__((ext_vector_type(4)));

// ws layout (_Float16 elements):
//   W1Th [HH][DD] @ 0        (hi of W1^T)
//   W1Tl [HH][DD] @ 32768    (lo*2048 of W1^T)
//   W2Th [DD][HH] @ 65536    (hi of W2^T)
//   W2Tl [DD][HH] @ 98304    (lo*2048 of W2^T)

__global__ __launch_bounds__(256) void prep_weights(
    const float* __restrict__ W1, const float* __restrict__ W2,
    _Float16* __restrict__ wsp) {
  int idx = blockIdx.x * 256 + threadIdx.x;  // 0..65535
  if (idx < HH * DD) {                       // W1[d][j]
    int d = idx / HH, j = idx % HH;
    float w0 = W1[idx];
    _Float16 h = (_Float16)w0;
    float r = (w0 - (float)h) * LO_SCALE;
    wsp[j * DD + d] = h;
    wsp[HH * DD + j * DD + d] = (_Float16)r;
  } else {                                   // W2[j][d]
    int k = idx - HH * DD;
    int j = k / DD, d = k % DD;
    float w0 = W2[k];
    _Float16 h = (_Float16)w0;
    float r = (w0 - (float)h) * LO_SCALE;
    wsp[2 * HH * DD + d * HH + j] = h;
    wsp[3 * HH * DD + d * HH + j] = (_Float16)r;
  }
}

__device__ __forceinline__ float fast_tanh(float x) {
  // tanh(x) = sign(x) * (1-e)/(1+e), e = 2^(-2*log2(e)*|x|)
  float e = __builtin_amdgcn_exp2f(-2.8853900817779268f * fabsf(x));
  float r = (1.0f - e) * __builtin_amdgcn_rcpf(1.0f + e);
  return copysignf(r, x);
}

__global__ __launch_bounds__(512, 2) void ode_mfma_kernel(
    const float* __restrict__ ts, const float* __restrict__ hxs,
    const float* __restrict__ masks, const float* __restrict__ b1,
    const float* __restrict__ b2, const _Float16* __restrict__ wsp,
    float* __restrict__ out) {
  // Z stride 520 halves: 16B-aligned rows; phase-B b128 reads land uniform
  // 8/bank (the wave64 b128 floor); phase-A b64 writes 2-way max (free, m136).
  __shared__ __align__(16) _Float16 Zh[BM][520], Zl[BM][520];
  __shared__ __align__(16) _Float16 Yh[BM][72], Yl[BM][72];
  __shared__ __align__(16) float DTs[BM][129];
  __shared__ __align__(16) _Float16 W2Lf[4 * 16 * 64 * 8];  // frag-major W2 lo

  const int t = threadIdx.x;
  const int w = t >> 6, l = t & 63;
  const int c = l & 15, q = l >> 4;
  const int m0 = blockIdx.x * BM;
  const int db = w >> 1, mb = w & 1;
  const int m = mb * 16 + c;       // phase-B owned sample
  const int d0 = db * 16 + 4 * q;  // phase-B owned dims d0..d0+3

  const _Float16* W1Th = wsp;
  const _Float16* W1Tl = wsp + HH * DD;
  const _Float16* W2Th = wsp + 2 * HH * DD;
  const _Float16* W2Tl = wsp + 3 * HH * DD;

  // ---- stationary weight fragments (loaded once; no global loads in loop) ----
  half8 w1h[4][2], w1l[4][2], w2h[16];
#pragma unroll
  for (int jl = 0; jl < 4; ++jl)
#pragma unroll
    for (int kk = 0; kk < 2; ++kk) {
      int off = ((4 * w + jl) * 16 + c) * DD + kk * 32 + 8 * q;
      w1h[jl][kk] = *(const half8*)&W1Th[off];
      w1l[jl][kk] = *(const half8*)&W1Tl[off];
    }
#pragma unroll
  for (int kk = 0; kk < 16; ++kk)
    w2h[kk] = *(const half8*)&W2Th[(db * 16 + c) * HH + kk * 32 + 8 * q];

  // W2 lo -> LDS, fragment-major (coalesced conflict-free reads); once
  if ((w & 1) == 0) {
#pragma unroll
    for (int kk = 0; kk < 16; ++kk) {
      half8 v = *(const half8*)&W2Tl[(db * 16 + c) * HH + kk * 32 + 8 * q];
      *(half8*)&W2Lf[((db * 16 + kk) * 64 + l) * 8] = v;
    }
  }

  // biases
  f32x4 b1f[4];
#pragma unroll
  for (int jl = 0; jl < 4; ++jl)
    b1f[jl] = *(const f32x4*)&b1[(4 * w + jl) * 16 + 4 * q];
  const f32x4 b2v = *(const f32x4*)&b2[d0];

  // dt table
  for (int idx = t; idx < BM * TT; idx += 512) {
    int mm = idx >> 7, s = idx & (TT - 1);
    float v = 0.0f;
    if (s < NSTEP) v = ts[(m0 + mm) * TT + s + 1] - ts[(m0 + mm) * TT + s];
    DTs[mm][s] = v;
  }

  // init state: y = hxs * mask (lane owns (m, d0..d0+3))
  const float mk = masks[m0 + m];
  f32x4 y0 = *(const f32x4*)&hxs[(m0 + m) * DD + d0];
  float y[4], f1[4], f2[4], f3[4];
  {
    half4 yh4, yl4;
#pragma unroll
    for (int r = 0; r < 4; ++r) {
      y[r] = y0[r] * mk;
      f1[r] = f2[r] = f3[r] = 0.0f;
      _Float16 h = (_Float16)y[r];
      yh4[r] = h;
      yl4[r] = (_Float16)((y[r] - (float)h) * LO_SCALE);
    }
    *(half4*)&Yh[m][d0] = yh4;
    *(half4*)&Yl[m][d0] = yl4;
  }
  __syncthreads();

  for (int s = 0; s < NSTEP; ++s) {
    // ---- phase A (swapped): Z^T tile = W1^T @ Y^T; lane -> (j=jb*16+4q+r, m=mbt*16+c)
#pragma unroll
    for (int mbt = 0; mbt < 2; ++mbt) {
      half8 yh[2], yl[2];
#pragma unroll
      for (int kk = 0; kk < 2; ++kk) {
        yh[kk] = *(const half8*)&Yh[mbt * 16 + c][kk * 32 + 8 * q];
        yl[kk] = *(const half8*)&Yl[mbt * 16 + c][kk * 32 + 8 * q];
      }
#pragma unroll
      for (int jl = 0; jl < 4; ++jl) {
        f32x4 acc1 = b1f[jl];
        f32x4 acc2 = {0.0f, 0.0f, 0.0f, 0.0f};
#pragma unroll
        for (int kk = 0; kk < 2; ++kk) {
          acc1 = __builtin_amdgcn_mfma_f32_16x16x32_f16(w1h[jl][kk], yh[kk], acc1, 0, 0, 0);
          acc2 = __builtin_amdgcn_mfma_f32_16x16x32_f16(w1h[jl][kk], yl[kk], acc2, 0, 0, 0);
          acc2 = __builtin_amdgcn_mfma_f32_16x16x32_f16(w1l[jl][kk], yh[kk], acc2, 0, 0, 0);
        }
        half4 zh4, zl4;
#pragma unroll
        for (int r = 0; r < 4; ++r) {
          float zf = fast_tanh(acc1[r] + acc2[r] * LO_INV);
          _Float16 h = (_Float16)zf;
          zh4[r] = h;
          zl4[r] = (_Float16)((zf - (float)h) * LO_SCALE);
        }
        const int row = mbt * 16 + c, colb = (4 * w + jl) * 16 + 4 * q;
        *(half4*)&Zh[row][colb] = zh4;  // 4 consecutive j -> one b64
        *(half4*)&Zl[row][colb] = zl4;
      }
    }
    __syncthreads();

    // ---- phase B (swapped): F^T = W2^T @ Z^T; one 16x16 tile/wave, K=512 ----
    f32x4 acc1 = b2v;
    f32x4 acc2 = {0.0f, 0.0f, 0.0f, 0.0f};
#pragma unroll
    for (int kk = 0; kk < 16; ++kk) {
      half8 zh = *(const half8*)&Zh[m][kk * 32 + 8 * q];
      half8 zl = *(const half8*)&Zl[m][kk * 32 + 8 * q];
      half8 w2l = *(const half8*)&W2Lf[((db * 16 + kk) * 64 + l) * 8];
      acc1 = __builtin_amdgcn_mfma_f32_16x16x32_f16(w2h[kk], zh, acc1, 0, 0, 0);
      acc2 = __builtin_amdgcn_mfma_f32_16x16x32_f16(w2h[kk], zl, acc2, 0, 0, 0);
      acc2 = __builtin_amdgcn_mfma_f32_16x16x32_f16(w2l, zh, acc2, 0, 0, 0);
    }
    {
      const float dtv = DTs[m][s];
      half4 yh4, yl4;
#pragma unroll
      for (int r = 0; r < 4; ++r) {
        float fn = acc1[r] + acc2[r] * LO_INV;
        float inc;
        if (s == 0)      inc = fn;
        else if (s == 1) inc = (3.0f * fn - f1[r]) * 0.5f;
        else if (s == 2) inc = (23.0f * fn - 16.0f * f1[r] + 5.0f * f2[r]) * (1.0f / 12.0f);
        else             inc = (55.0f * fn - 59.0f * f1[r] + 37.0f * f2[r] - 9.0f * f3[r]) * (1.0f / 24.0f);
        y[r] += dtv * inc;
        f3[r] = f2[r]; f2[r] = f1[r]; f1[r] = fn;
        _Float16 h = (_Float16)y[r];
        yh4[r] = h;
        yl4[r] = (_Float16)((y[r] - (float)h) * LO_SCALE);
      }
      *(half4*)&Yh[m][d0] = yh4;
      *(half4*)&Yl[m][d0] = yl4;
    }
    __syncthreads();
  }

  // pred = where(ts[:,0]==0, first_point, y_final)
  float ts0 = ts[(m0 + m) * TT];
  f32x4 o;
  if (ts0 == 0.0f) {
#pragma unroll
    for (int r = 0; r < 4; ++r) o[r] = y0[r] * mk;
  } else {
#pragma unroll
    for (int r = 0; r < 4; ++r) o[r] = y[r];
  }
  *(f32x4*)&out[(m0 + m) * DD + d0] = o;
}

extern "C" void kernel_launch(void* const* d_in, const int* in_sizes, int n_in,
                              void* d_out, int out_size, void* d_ws, size_t ws_size,
                              hipStream_t stream) {
  const float* ts    = (const float*)d_in[0];
  const float* hxs   = (const float*)d_in[1];
  const float* masks = (const float*)d_in[2];
  const float* W1    = (const float*)d_in[3];
  const float* b1    = (const float*)d_in[4];
  const float* W2    = (const float*)d_in[5];
  const float* b2    = (const float*)d_in[6];
  float* out = (float*)d_out;
  _Float16* wsp = (_Float16*)d_ws;
  (void)in_sizes; (void)n_in; (void)out_size; (void)ws_size;

  prep_weights<<<dim3((2 * HH * DD) / 256), dim3(256), 0, stream>>>(W1, W2, wsp);
  ode_mfma_kernel<<<dim3(NS / BM), dim3(512), 0, stream>>>(ts, hxs, masks, b1, b2, wsp, out);
}